// Round 12
// baseline (118.185 us; speedup 1.0000x reference)
//
#include <hip/hip_runtime.h>

#define DEV __device__ __forceinline__

typedef unsigned short u16;
typedef __attribute__((ext_vector_type(8))) __bf16 bf16x8;
typedef __attribute__((ext_vector_type(4))) float f32x4;
typedef __attribute__((ext_vector_type(8))) unsigned short u16x8;

DEV u16 f2bf(float f) {
  unsigned u = __builtin_bit_cast(unsigned, f);
  u += 0x7fffu + ((u >> 16) & 1u);
  return (u16)(u >> 16);
}
DEV float bf2f(u16 h) {
  unsigned u = ((unsigned)h) << 16;
  return __builtin_bit_cast(float, u);
}

DEV void gl_lds16(const void* gp, void* lp) {
  __builtin_amdgcn_global_load_lds(
      (__attribute__((address_space(1))) void*)(void*)gp,
      (__attribute__((address_space(3))) void*)lp, 16, 0, 0);
}

// ---------------- prep: a = tanh(a_raw); wq = [b;d] bf16; c -> bf16 --------------
__global__ __launch_bounds__(256) void prep_k(const float* __restrict__ a_raw,
                                              const float* __restrict__ b,
                                              const float* __restrict__ c,
                                              const float* __restrict__ d,
                                              float* __restrict__ af,
                                              u16* __restrict__ wq,
                                              u16* __restrict__ cw) {
  int i = blockIdx.x * 256 + threadIdx.x;
  if (i < 256) af[i] = tanhf(a_raw[i]);
  wq[i] = f2bf(b[i]);
  wq[65536 + i] = f2bf(d[i]);
  cw[i] = f2bf(c[i]);
}

// ---------------- u fp32 -> bf16, 8 elems/thread (measured ~15us, HBM-bound) ----
__global__ __launch_bounds__(256) void convu_k(const float* __restrict__ u,
                                               u16* __restrict__ ub) {
  size_t i = ((size_t)blockIdx.x * 256 + threadIdx.x) * 8;
  float4 v0 = *reinterpret_cast<const float4*>(u + i);
  float4 v1 = *reinterpret_cast<const float4*>(u + i + 4);
  u16x8 o;
  o[0] = f2bf(v0.x); o[1] = f2bf(v0.y); o[2] = f2bf(v0.z); o[3] = f2bf(v0.w);
  o[4] = f2bf(v1.x); o[5] = f2bf(v1.y); o[6] = f2bf(v1.z); o[7] = f2bf(v1.w);
  *reinterpret_cast<u16x8*>(ub + i) = o;
}

// ---------------- gemm1: [Bu|Ud] = ubf @ [b;d]^T + chunk carries ----------------
// EXACT R6 shape (measured ~21us at N=256): 256 thr / 4 waves (2x2), 128x128
// tile, BK=64, single-buffered, gl_lds both operands with pre-swizzled source.
// Extended to grid (4, 512): panel fastest (L2 reuse of the A rows).
// Panels 0,1 -> bu (R1-verified pre-swizzled global layout) + chunk carries
// (R3/R4/R6-verified); panels 2,3 -> ud plain row-major (R2/R3-verified).
__global__ __launch_bounds__(256) void gemm1_k(const u16* __restrict__ ubf,
                                               const u16* __restrict__ wq,
                                               const float* __restrict__ af,
                                               u16* __restrict__ bu,
                                               u16* __restrict__ ud,
                                               float* __restrict__ carry) {
  __shared__ u16 As[128 * 64];
  __shared__ u16 Bs[128 * 64];
  const int tid = threadIdx.x;
  const int lane = tid & 63;
  const int wid = tid >> 6;
  const int wm = wid >> 1, wn = wid & 1;
  const int panel = blockIdx.x;           // 0..3 over [b;d] rows
  const size_t row0 = (size_t)blockIdx.y * 128;
  const int col0 = panel * 128;

  const int rstg = tid >> 3;  // 0..31
  const int c16 = tid & 7;

  const f32x4 zero = {0.f, 0.f, 0.f, 0.f};
  f32x4 acc[4][4];
#pragma unroll
  for (int i = 0; i < 4; ++i)
#pragma unroll
    for (int j = 0; j < 4; ++j) acc[i][j] = zero;

#pragma unroll
  for (int kt = 0; kt < 4; ++kt) {
    const int kb = kt * 64;
#pragma unroll
    for (int j = 0; j < 4; ++j) {
      int row = j * 32 + rstg;
      int sc = c16 ^ (row & 7);
      gl_lds16(ubf + (row0 + row) * 256 + kb + sc * 8,
               (char*)As + j * 4096 + wid * 1024);
      gl_lds16(wq + (size_t)(col0 + row) * 256 + kb + sc * 8,
               (char*)Bs + j * 4096 + wid * 1024);
    }
    __syncthreads();
#pragma unroll
    for (int kk = 0; kk < 2; ++kk) {
      const int ks = kk * 4 + (lane >> 4);
      bf16x8 afr[4], bfr[4];
#pragma unroll
      for (int mi = 0; mi < 4; ++mi) {
        int ar = wm * 64 + mi * 16 + (lane & 15);
        afr[mi] = *reinterpret_cast<const bf16x8*>(&As[ar * 64 + (ks ^ (ar & 7)) * 8]);
      }
#pragma unroll
      for (int ni = 0; ni < 4; ++ni) {
        int br = wn * 64 + ni * 16 + (lane & 15);
        bfr[ni] = *reinterpret_cast<const bf16x8*>(&Bs[br * 64 + (ks ^ (br & 7)) * 8]);
      }
#pragma unroll
      for (int mi = 0; mi < 4; ++mi)
#pragma unroll
        for (int ni = 0; ni < 4; ++ni)
          acc[mi][ni] = __builtin_amdgcn_mfma_f32_16x16x32_bf16(
              afr[mi], bfr[ni], acc[mi][ni], 0, 0, 0);
    }
    if (kt < 3) __syncthreads();
  }

  if (panel < 2) {
    // ---- bu epilogue: pre-swizzled global layout (R1-verified; pairs with
    //      gemm2's linear gl_lds staging + swizzled XS reads) ----
#pragma unroll
    for (int mi = 0; mi < 4; ++mi) {
      int rl = wm * 64 + mi * 16 + (lane >> 4) * 4;
#pragma unroll
      for (int ni = 0; ni < 4; ++ni) {
        int col = col0 + wn * 64 + ni * 16 + (lane & 15);   // 0..255
#pragma unroll
        for (int q = 0; q < 4; ++q) {
          size_t R = row0 + rl + q;
          bu[R * 256 + (((col >> 3) ^ ((int)R & 7)) * 8) + (col & 7)] =
              f2bf(acc[mi][ni][q]);
        }
      }
    }
    // ---- chunk carry (R3/R4/R6-verified): t = mi*16 + (lane>>4)*4 + q ----
    const int chunk = (int)(blockIdx.y) * 2 + wm;
    const int tb = (lane >> 4) * 4;
#pragma unroll
    for (int ni = 0; ni < 4; ++ni) {
      int col = col0 + wn * 64 + ni * 16 + (lane & 15);
      float a = af[col];
      float c2 = a * a, c4 = c2 * c2, c8 = c4 * c4;
      float a12 = c8 * c4;
      float a13 = a12 * a;
      float base = (tb == 0) ? a12 : (tb == 4) ? c8 : (tb == 8) ? c4 : 1.0f;
      float p = base, s = 0.f;
#pragma unroll
      for (int mi = 3; mi >= 0; --mi) {
#pragma unroll
        for (int q = 3; q >= 0; --q) {
          s = fmaf(p, acc[mi][ni][q], s);
          if (q) p *= a;
        }
        if (mi) p *= a13;  // exponent +13: from (mi,q=0) to (mi-1,q=3)
      }
      s += __shfl_xor(s, 16, 64);
      s += __shfl_xor(s, 32, 64);
      if ((lane >> 4) == 0) carry[(size_t)chunk * 256 + col] = s;
    }
  } else {
    // ---- ud epilogue: plain row-major (R2/R3-verified) ----
#pragma unroll
    for (int mi = 0; mi < 4; ++mi) {
      int rl = wm * 64 + mi * 16 + (lane >> 4) * 4;
#pragma unroll
      for (int ni = 0; ni < 4; ++ni) {
        int col = col0 + wn * 64 + ni * 16 + (lane & 15);   // 256..511
#pragma unroll
        for (int q = 0; q < 4; ++q) {
          size_t R = row0 + rl + q;
          ud[R * 256 + (col - 256)] = f2bf(acc[mi][ni][q]);
        }
      }
    }
  }
}

// ---------------- scan2: exclusive scan of chunk carries (a^64 steps) -----------
__global__ __launch_bounds__(256) void scan2_k(const float* __restrict__ carry,
                                               const float* __restrict__ af,
                                               float* __restrict__ initb) {
  int b = blockIdx.x;  // 16
  int s = threadIdx.x;
  float a = af[s];
  float aL = a;
#pragma unroll
  for (int i = 0; i < 6; ++i) aL *= aL;  // a^64
  float x = 0.f;
  for (int k = 0; k < 64; ++k) {
    size_t idx = ((size_t)(b * 64 + k)) * 256 + s;
    float cv = carry[idx];
    initb[idx] = x;
    x = fmaf(aL, x, cv);
  }
}

// ---------------- gemm2: y = xs@c^T + Ud, in-LDS xs recon (R4 verbatim, ~22us) --
// grid (512, 2): bx = row tile (= chunk pair), by = col half. 512 thr, 8 waves
// 2x4, wave tile 64x32. LDS: XS [128][256] bf16 swizzled (64KB) + CS (16KB).
__global__ __launch_bounds__(512, 4) void gemm2_k(const u16* __restrict__ bu,
                                                  const u16* __restrict__ cw,
                                                  const u16* __restrict__ ud,
                                                  const float* __restrict__ af,
                                                  const float* __restrict__ initb,
                                                  float* __restrict__ y) {
  __shared__ u16 XS[128 * 256];
  __shared__ u16 CS[128 * 64];
  const int tid = threadIdx.x;
  const int lane = tid & 63;
  const int wid = tid >> 6;
  const int wr = wid >> 2, wc = wid & 3;
  const int bx = blockIdx.x;          // rows bx*128..+128 ; chunks 2bx, 2bx+1
  const int col0 = blockIdx.y * 128;

  // stage bu tile (linear copy; data pre-swizzled in global)
  const char* src = (const char*)bu + (size_t)bx * 65536;
#pragma unroll
  for (int j = 0; j < 8; ++j)
    gl_lds16(src + j * 8192 + tid * 16, (char*)XS + j * 8192 + wid * 1024);
  // stage C step 0
#pragma unroll
  for (int r = 0; r < 2; ++r) {
    int brow = r * 64 + (tid >> 3);
    int sc = (tid & 7) ^ (brow & 7);
    gl_lds16(cw + (size_t)(col0 + brow) * 256 + 0 + sc * 8,
             (char*)CS + r * 8192 + wid * 1024);
  }
  __syncthreads();

  // ---- recon xs in place: 2 chunk halves x 256 states ----
  {
    const int hf = tid >> 8;        // 0/1
    const int s = tid & 255;
    const float a = af[s];
    float x = initb[(size_t)(bx * 2 + hf) * 256 + s];
    const int r0 = hf * 64;
    const int slot = s >> 3;
    const int off = (s & 7);
#pragma unroll 8
    for (int t = 0; t < 64; ++t) {
      int r = r0 + t;
      int bi = r * 256 + ((slot ^ (r & 7)) * 8) + off;
      x = fmaf(a, x, bf2f(XS[bi]));
      XS[bi] = f2bf(x);
    }
  }

  // ---- init acc from ud (global, overlaps recon of other waves) ----
  f32x4 acc[4][2];
#pragma unroll
  for (int mi = 0; mi < 4; ++mi) {
    int rlb = wr * 64 + mi * 16 + (lane >> 4) * 4;
#pragma unroll
    for (int ni = 0; ni < 2; ++ni) {
      int col = col0 + wc * 32 + ni * 16 + (lane & 15);
#pragma unroll
      for (int q = 0; q < 4; ++q)
        acc[mi][ni][q] = bf2f(ud[(size_t)(bx * 128 + rlb + q) * 256 + col]);
    }
  }
  __syncthreads();

  // ---- K loop over c (K=256, 4 steps) ----
#pragma unroll
  for (int kt = 0; kt < 4; ++kt) {
#pragma unroll
    for (int kk = 0; kk < 2; ++kk) {
      const int ksl = kk * 4 + (lane >> 4);       // local slot in CS
      const int ksg = kt * 8 + ksl;               // global slot in XS
      bf16x8 afr[4], bfr[2];
#pragma unroll
      for (int mi = 0; mi < 4; ++mi) {
        int ar = wr * 64 + mi * 16 + (lane & 15);
        afr[mi] = *reinterpret_cast<const bf16x8*>(&XS[ar * 256 + ((ksg ^ (ar & 7)) * 8)]);
      }
#pragma unroll
      for (int ni = 0; ni < 2; ++ni) {
        int nr = wc * 32 + ni * 16 + (lane & 15);
        bfr[ni] = *reinterpret_cast<const bf16x8*>(&CS[nr * 64 + ((ksl ^ (nr & 7)) * 8)]);
      }
#pragma unroll
      for (int mi = 0; mi < 4; ++mi)
#pragma unroll
        for (int ni = 0; ni < 2; ++ni)
          acc[mi][ni] = __builtin_amdgcn_mfma_f32_16x16x32_bf16(
              afr[mi], bfr[ni], acc[mi][ni], 0, 0, 0);
    }
    if (kt < 3) {
      __syncthreads();  // readers done with CS
#pragma unroll
      for (int r = 0; r < 2; ++r) {
        int brow = r * 64 + (tid >> 3);
        int sc = (tid & 7) ^ (brow & 7);
        gl_lds16(cw + (size_t)(col0 + brow) * 256 + (kt + 1) * 64 + sc * 8,
                 (char*)CS + r * 8192 + wid * 1024);
      }
      __syncthreads();  // staged (vmcnt drained)
    }
  }

  // ---- epilogue: y fp32 ----
#pragma unroll
  for (int mi = 0; mi < 4; ++mi) {
    int rlb = wr * 64 + mi * 16 + (lane >> 4) * 4;
#pragma unroll
    for (int ni = 0; ni < 2; ++ni) {
      int col = col0 + wc * 32 + ni * 16 + (lane & 15);
#pragma unroll
      for (int q = 0; q < 4; ++q)
        y[(size_t)(bx * 128 + rlb + q) * 256 + col] = acc[mi][ni][q];
    }
  }
}

extern "C" void kernel_launch(void* const* d_in, const int* in_sizes, int n_in,
                              void* d_out, int out_size, void* d_ws, size_t ws_size,
                              hipStream_t stream) {
  const float* u = (const float*)d_in[0];
  const float* a_raw = (const float*)d_in[1];
  const float* b = (const float*)d_in[2];
  const float* c = (const float*)d_in[3];
  const float* d = (const float*)d_in[4];
  float* y = (float*)d_out;
  char* ws = (char*)d_ws;

  const size_t MB = 1u << 20;
  float* af = (float*)(ws);                       // 1 KB
  u16* wq = (u16*)(ws + 4096);                    // 256 KB ([b;d] stacked)
  u16* cw = (u16*)(ws + 4096 + 262144);           // 128 KB
  u16* ubf = (u16*)(ws + 1 * MB);                 // 32 MB
  u16* bu = (u16*)(ws + 33 * MB);                 // 32 MB (pre-swizzled)
  float* carry = (float*)(ws + 65 * MB);          // 1 MB
  float* initb = (float*)(ws + 66 * MB);          // 1 MB
  u16* ud = (u16*)(ws + 67 * MB);                 // 32 MB (plain row-major)

  prep_k<<<256, 256, 0, stream>>>(a_raw, b, c, d, af, wq, cw);
  convu_k<<<8192, 256, 0, stream>>>(u, ubf);
  gemm1_k<<<dim3(4, 512), 256, 0, stream>>>(ubf, wq, af, bu, ud, carry);
  scan2_k<<<16, 256, 0, stream>>>(carry, af, initb);
  gemm2_k<<<dim3(512, 2), 512, 0, stream>>>(bu, cw, ud, af, initb, y);
}